// Round 11
// baseline (352.128 us; speedup 1.0000x reference)
//
#include <hip/hip_runtime.h>
#include <math.h>

// x: (64,512,256) f32 -> 32768 tokens x 256 dims. codebook: (8192,256) f32.
#define N_TOK 32768
#define DDIM  256
#define KCB   8192
#define SLICES 4
#define KS     (KCB / SLICES)    // 2048 codes per slice
#define MARGIN 1.0f              // acc-scale gap guaranteeing exact winner
#define NFBLK  (N_TOK / 4)       // finalize blocks (1 token/wave, 4 waves)

typedef _Float16 half_t;
typedef half_t half8 __attribute__((ext_vector_type(8)));
typedef half_t half4 __attribute__((ext_vector_type(4)));
typedef float  f32x4 __attribute__((ext_vector_type(4)));
typedef float  f32x2 __attribute__((ext_vector_type(2)));

// ---------------------------------------------------------------------------
// P0: codebook f32 -> f16 copy + fp32 row norms.
__global__ __launch_bounds__(64) void prep_cb(const float* __restrict__ cb,
                                              half_t* __restrict__ cb16,
                                              float* __restrict__ cnorm) {
    int code = blockIdx.x;
    int lane = threadIdx.x;
    f32x4 v = *(const f32x4*)(cb + (size_t)code * DDIM + lane * 4);
    half4 h; h[0]=(half_t)v[0]; h[1]=(half_t)v[1]; h[2]=(half_t)v[2]; h[3]=(half_t)v[3];
    *(half4*)(cb16 + (size_t)code * DDIM + lane * 4) = h;
    float s = v[0]*v[0] + v[1]*v[1] + v[2]*v[2] + v[3]*v[3];
    #pragma unroll
    for (int off = 32; off > 0; off >>= 1) s += __shfl_down(s, off);
    if (lane == 0) cnorm[code] = s;
}

// load 8 consecutive f32, convert to 8 f16 (prologue only)
__device__ __forceinline__ half8 ldcvt8(const float* __restrict__ p) {
    f32x4 a = *(const f32x4*)p;
    f32x4 b = *(const f32x4*)(p + 4);
    half8 h;
    h[0]=(half_t)a[0]; h[1]=(half_t)a[1]; h[2]=(half_t)a[2]; h[3]=(half_t)a[3];
    h[4]=(half_t)b[0]; h[5]=(half_t)b[1]; h[6]=(half_t)b[2]; h[7]=(half_t)b[3];
    return h;
}

// pack: f32 key with low 13 mantissa bits replaced by code id (sortable)
__device__ __forceinline__ float packkey(float a, unsigned code) {
    return __uint_as_float((__float_as_uint(a) & 0xFFFFE000u) | code);
}

// ---------------------------------------------------------------------------
// Pass A — BARRIER-FREE register-streaming K-loop. 256 threads (4 waves),
// 256 tokens/block (64/wave), one 2048-code K-slice. A fragments persistent
// in regs (128); B fragments loaded per-lane DIRECTLY from the L2-resident
// f16 codebook (16B contiguous chunks: row (code)*512B + dk*64B; the 4 quads
// of a 16-lane group cover one aligned 64B line per code row). No LDS, no
// __syncthreads, no vmcnt(0) drain: waves are independent and the compiler
// can keep loads in flight across iterations (the m97-structure fix).
__global__ __launch_bounds__(256, 2)
void passA(const float* __restrict__ x, const half_t* __restrict__ cb16,
           const float* __restrict__ cnorm, float* __restrict__ cand) {

    const int tid  = threadIdx.x;
    const int w    = tid >> 6;
    const int lane = tid & 63;
    const int quad = lane >> 4;
    const int mcol = lane & 15;
    const int tokBase   = blockIdx.x * 256 + w * 64;   // wave's 64 tokens
    const int codeBase0 = blockIdx.y * KS;

    // ---- A fragments: A[m=mcol][k=quad*8+j], full D=256 in regs (128 regs)
    half8 afrag[4][8];
    #pragma unroll
    for (int rt = 0; rt < 4; rt++) {
        const float* xr = x + (size_t)(tokBase + rt * 16 + mcol) * DDIM + quad * 8;
        #pragma unroll
        for (int dk = 0; dk < 8; dk++)
            afrag[rt][dk] = ldcvt8(xr + dk * 32);
    }

    // packed top-2 keys (max semantics) per owned token [rt][r]
    float k0[4][4], k1[4][4];
    #pragma unroll
    for (int rt = 0; rt < 4; rt++)
        #pragma unroll
        for (int r = 0; r < 4; r++) { k0[rt][r] = -INFINITY; k1[rt][r] = -INFINITY; }

    // lane's B row base: code row (codeBase0 + mcol), dim chunk quad*8
    const half_t* brow = cb16 + (size_t)(codeBase0 + mcol) * DDIM + quad * 8;
    const float*  cnp  = cnorm + codeBase0 + mcol;

    for (int ct = 0; ct < KS / 32; ct++) {           // 64 iterations, 32 codes each
        const half_t* r0 = brow + (size_t)ct * 32 * DDIM;
        const half_t* r1 = r0 + 16 * DDIM;
        const float mc0 = -0.5f * cnp[ct * 32];
        const float mc1 = -0.5f * cnp[ct * 32 + 16];

        f32x4 acc[2][4];
        #pragma unroll
        for (int rt = 0; rt < 4; rt++) {
            acc[0][rt][0]=mc0; acc[0][rt][1]=mc0; acc[0][rt][2]=mc0; acc[0][rt][3]=mc0;
            acc[1][rt][0]=mc1; acc[1][rt][1]=mc1; acc[1][rt][2]=mc1; acc[1][rt][3]=mc1;
        }
        #pragma unroll
        for (int dk = 0; dk < 8; dk++) {
            half8 bf0 = *(const half8*)(r0 + dk * 32);   // 16B, offset dk*64B
            half8 bf1 = *(const half8*)(r1 + dk * 32);
            #pragma unroll
            for (int rt = 0; rt < 4; rt++) {
                acc[0][rt] = __builtin_amdgcn_mfma_f32_16x16x32_f16(afrag[rt][dk], bf0, acc[0][rt], 0, 0, 0);
                acc[1][rt] = __builtin_amdgcn_mfma_f32_16x16x32_f16(afrag[rt][dk], bf1, acc[1][rt], 0, 0, 0);
            }
        }
        // C layout: col = lane&15 (code), row = quad*4 + r (token).
        const unsigned code0 = (unsigned)(codeBase0 + ct * 32 + mcol);
        const unsigned code1 = code0 + 16;
        #pragma unroll
        for (int rt = 0; rt < 4; rt++)
            #pragma unroll
            for (int r = 0; r < 4; r++) {
                float a = packkey(acc[0][rt][r], code0);
                float b = packkey(acc[1][rt][r], code1);
                k1[rt][r] = fmaxf(k1[rt][r], __builtin_amdgcn_fmed3f(k0[rt][r], a, b));
                k0[rt][r] = fmaxf(fmaxf(k0[rt][r], a), b);
            }
    }

    // ---- merge top-2 (max) across the 16 class lanes; lane mcol==0 writes.
    #pragma unroll
    for (int s = 1; s < 16; s <<= 1) {
        #pragma unroll
        for (int rt = 0; rt < 4; rt++)
            #pragma unroll
            for (int r = 0; r < 4; r++) {
                float o0 = __shfl_xor(k0[rt][r], s, 64);
                float o1 = __shfl_xor(k1[rt][r], s, 64);
                float n1 = fmaxf(fminf(k0[rt][r], o0), fmaxf(k1[rt][r], o1));
                k0[rt][r] = fmaxf(k0[rt][r], o0);
                k1[rt][r] = n1;
            }
    }
    if (mcol == 0) {
        #pragma unroll
        for (int rt = 0; rt < 4; rt++)
            #pragma unroll
            for (int r = 0; r < 4; r++) {
                int token = tokBase + rt * 16 + quad * 4 + r;
                f32x2 kk; kk[0] = k0[rt][r]; kk[1] = k1[rt][r];
                *(f32x2*)&cand[(size_t)token * (SLICES * 2) + blockIdx.y * 2] = kk;
            }
    }
}

// ---------------------------------------------------------------------------
// K2: 1 token/wave. Fast path: best key beats 2nd by > MARGIN -> winner
// certain, gather only. Slow path: exact fp32 re-score of in-margin
// candidates only (others provably cannot win). Loss partial: plain
// per-block store (no contended atomic).
__global__ __launch_bounds__(256) void finalize_kernel(
    const float* __restrict__ x, const float* __restrict__ cb,
    const float* __restrict__ cnorm, const float* __restrict__ cand,
    float* __restrict__ out, float* __restrict__ partials) {

    const int tid = threadIdx.x, w = tid >> 6, lane = tid & 63;
    const int token = blockIdx.x * 4 + w;
    const float* xrow = x + (size_t)token * DDIM;

    f32x4 ka = *(const f32x4*)(cand + (size_t)token * 8);
    f32x4 kb = *(const f32x4*)(cand + (size_t)token * 8 + 4);
    float v[8] = {ka[0], ka[1], ka[2], ka[3], kb[0], kb[1], kb[2], kb[3]};
    float t0 = -INFINITY, t1 = -INFINITY;
    #pragma unroll
    for (int j = 0; j < 8; j++) {
        float m = fminf(t0, v[j]);
        t0 = fmaxf(t0, v[j]);
        t1 = fmaxf(t1, m);
    }
    int bidx = (int)(__float_as_uint(t0) & 0x1FFFu);

    if (!(t0 - t1 > MARGIN)) {
        const int j = lane >> 3, sub = lane & 7;
        int  cj   = (int)(__float_as_uint(v[j]) & 0x1FFFu);
        bool live = (v[j] >= t0 - MARGIN);
        float p = 0.0f;
        if (live) {
            const float* crow = cb + (size_t)cj * DDIM;
            #pragma unroll
            for (int c = 0; c < 8; c++) {
                f32x4 xa = *(const f32x4*)(xrow + c * 32 + sub * 4);
                f32x4 ca = *(const f32x4*)(crow + c * 32 + sub * 4);
                p += xa[0]*ca[0] + xa[1]*ca[1] + xa[2]*ca[2] + xa[3]*ca[3];
            }
        }
        p += __shfl_xor(p, 1, 64);
        p += __shfl_xor(p, 2, 64);
        p += __shfl_xor(p, 4, 64);
        float bd = live ? (cnorm[cj] - 2.0f * p) : INFINITY;
        int   bi = cj;
        #pragma unroll
        for (int s = 8; s < 64; s <<= 1) {   // reference tie-break: lower index
            float od = __shfl_xor(bd, s, 64);
            int   oi = __shfl_xor(bi, s, 64);
            if (od < bd || (od == bd && oi < bi)) { bd = od; bi = oi; }
        }
        bidx = bi;
    }

    f32x4 cv = *(const f32x4*)(cb + (size_t)bidx * DDIM + lane * 4);
    f32x4 xv = *(const f32x4*)(xrow + lane * 4);
    *(f32x4*)(out + (size_t)token * DDIM + lane * 4) = cv;
    float d0 = cv[0]-xv[0], d1 = cv[1]-xv[1], d2 = cv[2]-xv[2], d3 = cv[3]-xv[3];
    float lsum = d0*d0 + d1*d1 + d2*d2 + d3*d3;

    __shared__ float red[256];
    red[tid] = lsum;
    __syncthreads();
    #pragma unroll
    for (int s = 128; s > 0; s >>= 1) {
        if (tid < s) red[tid] += red[tid + s];
        __syncthreads();
    }
    if (tid == 0) partials[blockIdx.x] = red[0];
}

// ---------------------------------------------------------------------------
// K3: single-block sum of the 8192 per-block loss partials.
__global__ __launch_bounds__(256) void reduce_loss(const float* __restrict__ partials,
                                                   float* __restrict__ out) {
    const int tid = threadIdx.x;
    float s = 0.0f;
    #pragma unroll
    for (int i = 0; i < 8; i++) {
        f32x4 v = *(const f32x4*)(partials + (size_t)(i * 256 + tid) * 4);
        s += v[0] + v[1] + v[2] + v[3];
    }
    __shared__ float red[256];
    red[tid] = s;
    __syncthreads();
    #pragma unroll
    for (int st = 128; st > 0; st >>= 1) {
        if (tid < st) red[tid] += red[tid + st];
        __syncthreads();
    }
    if (tid == 0)
        out[(size_t)N_TOK * DDIM] = red[0] * (0.25f / (float)((size_t)N_TOK * DDIM));
}

// ---------------------------------------------------------------------------
extern "C" void kernel_launch(void* const* d_in, const int* in_sizes, int n_in,
                              void* d_out, int out_size, void* d_ws, size_t ws_size,
                              hipStream_t stream) {
    const float* x  = (const float*)d_in[0];
    const float* cb = (const float*)d_in[1];
    float* out = (float*)d_out;

    // ws: cb16 (4 MB f16) | cnorm[8192] | cand[32768*8] | partials[8192]
    half_t* cb16     = (half_t*)d_ws;
    float*  cnorm    = (float*)(cb16 + (size_t)KCB * DDIM);
    float*  cand     = cnorm + KCB;
    float*  partials = cand + (size_t)N_TOK * 8;

    prep_cb<<<KCB, 64, 0, stream>>>(cb, cb16, cnorm);
    dim3 gA(N_TOK / 256, SLICES);
    passA<<<gA, 256, 0, stream>>>(x, cb16, cnorm, cand);
    finalize_kernel<<<NFBLK, 256, 0, stream>>>(x, cb, cnorm, cand, out, partials);
    reduce_loss<<<1, 256, 0, stream>>>(partials, out);
}

// Round 12
// 228.781 us; speedup vs baseline: 1.5391x; 1.5391x over previous
//
#include <hip/hip_runtime.h>
#include <math.h>

// x: (64,512,256) f32 -> 32768 tokens x 256 dims. codebook: (8192,256) f32.
#define N_TOK 32768
#define DDIM  256
#define KCB   8192
#define SLICES 4
#define KS     (KCB / SLICES)    // 2048 codes per slice
#define TCODES 32                // codes per LDS tile
#define NSTEP  (KS / TCODES)     // 64 tiles per slice
#define MARGIN 1.0f              // acc-scale gap guaranteeing exact winner
#define NFBLK  (N_TOK / 4)       // finalize blocks (1 token/wave, 4 waves)

typedef _Float16 half_t;
typedef half_t half8 __attribute__((ext_vector_type(8)));
typedef half_t half4 __attribute__((ext_vector_type(4)));
typedef float  f32x4 __attribute__((ext_vector_type(4)));
typedef float  f32x2 __attribute__((ext_vector_type(2)));

// ---------------------------------------------------------------------------
// P0: codebook f32 -> f16 copy + fp32 row norms.
__global__ __launch_bounds__(64) void prep_cb(const float* __restrict__ cb,
                                              half_t* __restrict__ cb16,
                                              float* __restrict__ cnorm) {
    int code = blockIdx.x;
    int lane = threadIdx.x;
    f32x4 v = *(const f32x4*)(cb + (size_t)code * DDIM + lane * 4);
    half4 h; h[0]=(half_t)v[0]; h[1]=(half_t)v[1]; h[2]=(half_t)v[2]; h[3]=(half_t)v[3];
    *(half4*)(cb16 + (size_t)code * DDIM + lane * 4) = h;
    float s = v[0]*v[0] + v[1]*v[1] + v[2]*v[2] + v[3]*v[3];
    #pragma unroll
    for (int off = 32; off > 0; off >>= 1) s += __shfl_down(s, off);
    if (lane == 0) cnorm[code] = s;
}

// load 8 consecutive f32, convert to 8 f16 (prologue only)
__device__ __forceinline__ half8 ldcvt8(const float* __restrict__ p) {
    f32x4 a = *(const f32x4*)p;
    f32x4 b = *(const f32x4*)(p + 4);
    half8 h;
    h[0]=(half_t)a[0]; h[1]=(half_t)a[1]; h[2]=(half_t)a[2]; h[3]=(half_t)a[3];
    h[4]=(half_t)b[0]; h[5]=(half_t)b[1]; h[6]=(half_t)b[2]; h[7]=(half_t)b[3];
    return h;
}

// pack: f32 key with low 13 mantissa bits replaced by code id (sortable)
__device__ __forceinline__ float packkey(float a, unsigned code) {
    return __uint_as_float((__float_as_uint(a) & 0xFFFFE000u) | code);
}

// ---------------------------------------------------------------------------
// Pass A — shared-LDS K-loop with register prefetch (cheap barriers).
// 256 threads (4 waves), 256 tokens/block (64/wave), one 2048-code K-slice.
// A fragments persistent in regs (128). B staged cooperatively: LOAD pulls
// the nt+2 tile global->regs right AFTER the barrier (in flight across the
// whole compute body); COMMIT writes regs->LDS (other buffer) before the
// barrier, so its vmcnt wait is free and the barrier drains only the
// ds_write lgkmcnt — the structural vmcnt(0) drain of global_load_lds
// staging (r8's ~50% stall) is gone. LDS sharing keeps the 4x L2-traffic
// amplification that r11's LDS-free version lost (8.4 GB -> 1 GB).
__global__ __launch_bounds__(256, 2)
void passA(const float* __restrict__ x, const half_t* __restrict__ cb16,
           const float* __restrict__ cnorm, float* __restrict__ cand) {

    __shared__ __align__(16) half_t buf[2][TCODES * 256];   // 2 x 16 KB

    const int tid  = threadIdx.x;
    const int w    = tid >> 6;
    const int lane = tid & 63;
    const int quad = lane >> 4;
    const int mcol = lane & 15;
    const int tokBase   = blockIdx.x * 256 + w * 64;   // wave's 64 tokens
    const int codeBase0 = blockIdx.y * KS;

    // ---- A fragments: A[m=mcol][k=quad*8+j], full D=256 in regs (128 regs)
    half8 afrag[4][8];
    #pragma unroll
    for (int rt = 0; rt < 4; rt++) {
        const float* xr = x + (size_t)(tokBase + rt * 16 + mcol) * DDIM + quad * 8;
        #pragma unroll
        for (int dk = 0; dk < 8; dk++)
            afrag[rt][dk] = ldcvt8(xr + dk * 32);
    }

    // ---- B-read LDS offsets (halves): row = mcol, chunk = (dk*4+quad)^(mcol&7)
    int boff[8];
    #pragma unroll
    for (int dk = 0; dk < 8; dk++)
        boff[dk] = mcol * 256 + (((dk * 4 + quad) ^ (mcol & 7)) * 8);

    // packed top-2 keys (max semantics) per owned token [rt][r]
    float k0[4][4], k1[4][4];
    #pragma unroll
    for (int rt = 0; rt < 4; rt++)
        #pragma unroll
        for (int r = 0; r < 4; r++) { k0[rt][r] = -INFINITY; k1[rt][r] = -INFINITY; }

    // ---- staging: 16 KB tile = 1024 x 16B chunks, 4/thread.
    // dest chunk = o*256 + tid; source chunk c in row r XOR-swizzled to match
    // the read side (r = D>>5, c = (D&31)^(r&7)).
    const char* cbbase = (const char*)(cb16 + (size_t)codeBase0 * DDIM);
    int goff[4];
    #pragma unroll
    for (int o = 0; o < 4; o++) {
        int L = o * 256 + tid, r = L >> 5, c = (L & 31) ^ (r & 7);
        goff[o] = r * 512 + c * 16;
    }
    half8 pf[4];
    #define LOAD(nt)                                                            \
        {                                                                       \
            const char* srcb = cbbase + (size_t)(nt) * (TCODES * 512);          \
            _Pragma("unroll")                                                   \
            for (int o = 0; o < 4; o++)                                         \
                pf[o] = *(const half8*)(srcb + goff[o]);                        \
        }
    #define COMMIT(b)                                                           \
        {                                                                       \
            _Pragma("unroll")                                                   \
            for (int o = 0; o < 4; o++)                                         \
                *(half8*)&buf[b][(o * 256 + tid) * 8] = pf[o];                  \
        }

    LOAD(0)
    COMMIT(0)
    __syncthreads();
    LOAD(1)

    for (int nt = 0; nt < NSTEP; nt++) {
        const half_t* cur = buf[nt & 1];
        const int codeBase = codeBase0 + nt * TCODES;
        const float mc0 = -0.5f * cnorm[codeBase + mcol];
        const float mc1 = -0.5f * cnorm[codeBase + 16 + mcol];

        f32x4 acc[2][4];
        #pragma unroll
        for (int rt = 0; rt < 4; rt++) {
            acc[0][rt][0]=mc0; acc[0][rt][1]=mc0; acc[0][rt][2]=mc0; acc[0][rt][3]=mc0;
            acc[1][rt][0]=mc1; acc[1][rt][1]=mc1; acc[1][rt][2]=mc1; acc[1][rt][3]=mc1;
        }
        const half_t* crow0 = cur;
        const half_t* crow1 = cur + 16 * 256;
        #pragma unroll
        for (int dk = 0; dk < 8; dk++) {
            half8 bf0 = *(const half8*)(crow0 + boff[dk]);
            half8 bf1 = *(const half8*)(crow1 + boff[dk]);
            #pragma unroll
            for (int rt = 0; rt < 4; rt++) {
                acc[0][rt] = __builtin_amdgcn_mfma_f32_16x16x32_f16(afrag[rt][dk], bf0, acc[0][rt], 0, 0, 0);
                acc[1][rt] = __builtin_amdgcn_mfma_f32_16x16x32_f16(afrag[rt][dk], bf1, acc[1][rt], 0, 0, 0);
            }
        }
        // C layout: col = lane&15 (code), row = quad*4 + r (token).
        const unsigned code0 = (unsigned)(codeBase + mcol);
        const unsigned code1 = code0 + 16;
        #pragma unroll
        for (int rt = 0; rt < 4; rt++)
            #pragma unroll
            for (int r = 0; r < 4; r++) {
                float a = packkey(acc[0][rt][r], code0);
                float b = packkey(acc[1][rt][r], code1);
                k1[rt][r] = fmaxf(k1[rt][r], __builtin_amdgcn_fmed3f(k0[rt][r], a, b));
                k0[rt][r] = fmaxf(fmaxf(k0[rt][r], a), b);
            }

        // pipeline: commit prefetched tile nt+1 into the other buffer (its
        // loads have been in flight for a full body -> vmcnt wait is free),
        // barrier (drains only ds_write lgkmcnt), then launch loads for nt+2.
        if (nt + 1 < NSTEP) COMMIT((nt + 1) & 1)
        __syncthreads();
        if (nt + 2 < NSTEP) LOAD(nt + 2)
    }

    // ---- merge top-2 (max) across the 16 class lanes; lane mcol==0 writes.
    #pragma unroll
    for (int s = 1; s < 16; s <<= 1) {
        #pragma unroll
        for (int rt = 0; rt < 4; rt++)
            #pragma unroll
            for (int r = 0; r < 4; r++) {
                float o0 = __shfl_xor(k0[rt][r], s, 64);
                float o1 = __shfl_xor(k1[rt][r], s, 64);
                float n1 = fmaxf(fminf(k0[rt][r], o0), fmaxf(k1[rt][r], o1));
                k0[rt][r] = fmaxf(k0[rt][r], o0);
                k1[rt][r] = n1;
            }
    }
    if (mcol == 0) {
        #pragma unroll
        for (int rt = 0; rt < 4; rt++)
            #pragma unroll
            for (int r = 0; r < 4; r++) {
                int token = tokBase + rt * 16 + quad * 4 + r;
                f32x2 kk; kk[0] = k0[rt][r]; kk[1] = k1[rt][r];
                *(f32x2*)&cand[(size_t)token * (SLICES * 2) + blockIdx.y * 2] = kk;
            }
    }
}

// ---------------------------------------------------------------------------
// K2: 1 token/wave. Fast path: best key beats 2nd by > MARGIN -> winner
// certain, gather only. Slow path: exact fp32 re-score of in-margin
// candidates only. Loss partial: plain per-block store (no contended atomic).
__global__ __launch_bounds__(256) void finalize_kernel(
    const float* __restrict__ x, const float* __restrict__ cb,
    const float* __restrict__ cnorm, const float* __restrict__ cand,
    float* __restrict__ out, float* __restrict__ partials) {

    const int tid = threadIdx.x, w = tid >> 6, lane = tid & 63;
    const int token = blockIdx.x * 4 + w;
    const float* xrow = x + (size_t)token * DDIM;

    f32x4 ka = *(const f32x4*)(cand + (size_t)token * 8);
    f32x4 kb = *(const f32x4*)(cand + (size_t)token * 8 + 4);
    float v[8] = {ka[0], ka[1], ka[2], ka[3], kb[0], kb[1], kb[2], kb[3]};
    float t0 = -INFINITY, t1 = -INFINITY;
    #pragma unroll
    for (int j = 0; j < 8; j++) {
        float m = fminf(t0, v[j]);
        t0 = fmaxf(t0, v[j]);
        t1 = fmaxf(t1, m);
    }
    int bidx = (int)(__float_as_uint(t0) & 0x1FFFu);

    if (!(t0 - t1 > MARGIN)) {
        const int j = lane >> 3, sub = lane & 7;
        int  cj   = (int)(__float_as_uint(v[j]) & 0x1FFFu);
        bool live = (v[j] >= t0 - MARGIN);
        float p = 0.0f;
        if (live) {
            const float* crow = cb + (size_t)cj * DDIM;
            #pragma unroll
            for (int c = 0; c < 8; c++) {
                f32x4 xa = *(const f32x4*)(xrow + c * 32 + sub * 4);
                f32x4 ca = *(const f32x4*)(crow + c * 32 + sub * 4);
                p += xa[0]*ca[0] + xa[1]*ca[1] + xa[2]*ca[2] + xa[3]*ca[3];
            }
        }
        p += __shfl_xor(p, 1, 64);
        p += __shfl_xor(p, 2, 64);
        p += __shfl_xor(p, 4, 64);
        float bd = live ? (cnorm[cj] - 2.0f * p) : INFINITY;
        int   bi = cj;
        #pragma unroll
        for (int s = 8; s < 64; s <<= 1) {   // reference tie-break: lower index
            float od = __shfl_xor(bd, s, 64);
            int   oi = __shfl_xor(bi, s, 64);
            if (od < bd || (od == bd && oi < bi)) { bd = od; bi = oi; }
        }
        bidx = bi;
    }

    f32x4 cv = *(const f32x4*)(cb + (size_t)bidx * DDIM + lane * 4);
    f32x4 xv = *(const f32x4*)(xrow + lane * 4);
    *(f32x4*)(out + (size_t)token * DDIM + lane * 4) = cv;
    float d0 = cv[0]-xv[0], d1 = cv[1]-xv[1], d2 = cv[2]-xv[2], d3 = cv[3]-xv[3];
    float lsum = d0*d0 + d1*d1 + d2*d2 + d3*d3;

    __shared__ float red[256];
    red[tid] = lsum;
    __syncthreads();
    #pragma unroll
    for (int s = 128; s > 0; s >>= 1) {
        if (tid < s) red[tid] += red[tid + s];
        __syncthreads();
    }
    if (tid == 0) partials[blockIdx.x] = red[0];
}

// ---------------------------------------------------------------------------
// K3: single-block sum of the 8192 per-block loss partials.
__global__ __launch_bounds__(256) void reduce_loss(const float* __restrict__ partials,
                                                   float* __restrict__ out) {
    const int tid = threadIdx.x;
    float s = 0.0f;
    #pragma unroll
    for (int i = 0; i < 8; i++) {
        f32x4 v = *(const f32x4*)(partials + (size_t)(i * 256 + tid) * 4);
        s += v[0] + v[1] + v[2] + v[3];
    }
    __shared__ float red[256];
    red[tid] = s;
    __syncthreads();
    #pragma unroll
    for (int st = 128; st > 0; st >>= 1) {
        if (tid < st) red[tid] += red[tid + st];
        __syncthreads();
    }
    if (tid == 0)
        out[(size_t)N_TOK * DDIM] = red[0] * (0.25f / (float)((size_t)N_TOK * DDIM));
}

// ---------------------------------------------------------------------------
extern "C" void kernel_launch(void* const* d_in, const int* in_sizes, int n_in,
                              void* d_out, int out_size, void* d_ws, size_t ws_size,
                              hipStream_t stream) {
    const float* x  = (const float*)d_in[0];
    const float* cb = (const float*)d_in[1];
    float* out = (float*)d_out;

    // ws: cb16 (4 MB f16) | cnorm[8192] | cand[32768*8] | partials[8192]
    half_t* cb16     = (half_t*)d_ws;
    float*  cnorm    = (float*)(cb16 + (size_t)KCB * DDIM);
    float*  cand     = cnorm + KCB;
    float*  partials = cand + (size_t)N_TOK * 8;

    prep_cb<<<KCB, 64, 0, stream>>>(cb, cb16, cnorm);
    dim3 gA(N_TOK / 256, SLICES);
    passA<<<gA, 256, 0, stream>>>(x, cb16, cnorm, cand);
    finalize_kernel<<<NFBLK, 256, 0, stream>>>(x, cb, cnorm, cand, out, partials);
    reduce_loss<<<1, 256, 0, stream>>>(partials, out);
}